// Round 2
// 555.237 us; speedup vs baseline: 1.0446x; 1.0446x over previous
//
#include <hip/hip_runtime.h>
#include <cstdint>
#include <cstddef>

// out = x @ weight_real^T + bias
// (magnitude*cos(phase) == real, identically; weight_imag is dead.)
//
// R4: resubmit of R3 (container failed twice = infra signature; kernel
// re-audited: barrier uniformity, vmcnt ledger, LDS WAR hazards, swizzle
// round-trip, OOB — all clean). 256^2 8-phase template:
//   T2  LDS XOR-swizzle (k-chunk c ^= row&7), inverse swizzle on the global
//       source so global_load_lds keeps a linear wave-uniform dest.
//   T3/T4 4 phases per K-tile, one half-tile staged per phase, counted
//       s_waitcnt vmcnt(6) at K-tile boundaries only (never 0 in the loop).
//   T5  s_setprio(1) around each 16-MFMA cluster.
// 512 threads = 8 waves (2M x 4N), per-wave output 128x64, 128 KiB LDS.

#define TILE 128   // fallback kernel tile
#define BK 64
#define BM 256
#define BN 256

typedef short bf16x8 __attribute__((ext_vector_type(8)));  // 8 bf16 in 4 VGPRs
typedef float f32x4 __attribute__((ext_vector_type(4)));

__device__ __forceinline__ unsigned short f2bf(float f) {
  // round-to-nearest-even fp32 -> bf16
  unsigned int x = __float_as_uint(f);
  unsigned int r = x + 0x7FFFu + ((x >> 16) & 1u);
  return (unsigned short)(r >> 16);
}

// Converts x (nA8 chunks of 8 floats) then wr (nB8 chunks) in one kernel.
__global__ void cvt_both_f32_to_bf16(const float* __restrict__ x,
                                     const float* __restrict__ wr,
                                     unsigned short* __restrict__ xa,
                                     unsigned short* __restrict__ wb,
                                     int nA8, int nB8) {
  int i = blockIdx.x * blockDim.x + threadIdx.x;
  int stride = gridDim.x * blockDim.x;
  int total = nA8 + nB8;
  for (; i < total; i += stride) {
    const float* src; unsigned short* dst; int j;
    if (i < nA8) { src = x;  dst = xa; j = i; }
    else         { src = wr; dst = wb; j = i - nA8; }
    float4 a = ((const float4*)src)[2 * j];
    float4 b = ((const float4*)src)[2 * j + 1];
    union { unsigned short u[8]; uint4 v; } o;
    o.u[0] = f2bf(a.x); o.u[1] = f2bf(a.y);
    o.u[2] = f2bf(a.z); o.u[3] = f2bf(a.w);
    o.u[4] = f2bf(b.x); o.u[5] = f2bf(b.y);
    o.u[6] = f2bf(b.z); o.u[7] = f2bf(b.w);
    ((uint4*)dst)[j] = o.v;
  }
}

// ---------------- 256^2 8-phase GEMM ----------------
// LDS tile per buffer: [256 rows][64 k] bf16 (32 KB). 16B chunk c of row r
// holds global k-chunk (c ^ (r&7)) -> ds_read banks spread uniformly.

__device__ __forceinline__ void bar() {
  asm volatile("" ::: "memory");
  __builtin_amdgcn_s_barrier();
  asm volatile("" ::: "memory");
}

// Stage one 128-row half-tile (16 KB) = 2 global_load_lds per thread.
__device__ __forceinline__ void stage_half(const unsigned short* __restrict__ g0,
                                           unsigned short* lds_region, int half,
                                           int k0, int K, int tid, int wave) {
#pragma unroll
  for (int l = 0; l < 2; ++l) {
    int e = l * 512 + tid;                // 16B-chunk index within the half
    int r = e >> 3;                       // row in half (0..127)
    int ks = ((e ^ (e >> 3)) & 7) << 3;   // inverse-swizzled k source (elems)
    const unsigned short* g = g0 + (size_t)(half * 128 + r) * K + (k0 + ks);
    unsigned short* ld = lds_region + half * (128 * 64)
                         + (size_t)(l * 512 + (wave << 6)) * 8;  // wave-uniform
    __builtin_amdgcn_global_load_lds(
        (const __attribute__((address_space(1))) void*)g,
        (__attribute__((address_space(3))) void*)ld, 16, 0, 0);
  }
}

// Swizzled fragment read: row R, k-chunk c (= h*4+quad), 16 B.
__device__ __forceinline__ bf16x8 ld_frag(const unsigned short* region, int R, int c) {
  return *(const bf16x8*)&region[R * 64 + (((c ^ R) & 7) << 3)];
}

__global__ __launch_bounds__(512, 2) void gemm256_bt_bf16(
    const unsigned short* __restrict__ Abf, const unsigned short* __restrict__ Bbf,
    const float* __restrict__ bias, float* __restrict__ C, int M, int N, int K) {
  __shared__ unsigned short sA[2][BM * BK];  // 2 x 32 KB
  __shared__ unsigned short sB[2][BM * BK];  // 2 x 32 KB

  const int tid = threadIdx.x;
  const int wave = tid >> 6, lane = tid & 63;
  const int lrow = lane & 15, quad = lane >> 4;
  const int wm = wave >> 2, wn = wave & 3;  // 2 x 4 wave grid
  const int row0 = blockIdx.y * BM, col0 = blockIdx.x * BN;
  const unsigned short* Ag = Abf + (size_t)row0 * K;
  const unsigned short* Bg = Bbf + (size_t)col0 * K;
  const int NT = K / BK;

  f32x4 acc[8][4];
  const f32x4 zf = {0.f, 0.f, 0.f, 0.f};
#pragma unroll
  for (int i = 0; i < 8; ++i)
#pragma unroll
    for (int j = 0; j < 4; ++j) acc[i][j] = zf;

  // Prologue. Stream order per tile: B0,B1,A0,A1. Issue tile0's 4 halves +
  // tile1's first 3 (14 loads); vmcnt(6) completes exactly tile0, leaving
  // 3 half-tiles (6 loads) in flight — the steady-state invariant.
  stage_half(Bg, &sB[0][0], 0, 0, K, tid, wave);
  stage_half(Bg, &sB[0][0], 1, 0, K, tid, wave);
  stage_half(Ag, &sA[0][0], 0, 0, K, tid, wave);
  stage_half(Ag, &sA[0][0], 1, 0, K, tid, wave);
  if (NT > 1) {
    stage_half(Bg, &sB[1][0], 0, BK, K, tid, wave);
    stage_half(Bg, &sB[1][0], 1, BK, K, tid, wave);
    stage_half(Ag, &sA[1][0], 0, BK, K, tid, wave);
    asm volatile("s_waitcnt vmcnt(6)" ::: "memory");
  } else {
    asm volatile("s_waitcnt vmcnt(0)" ::: "memory");
  }
  bar();

  int buf = 0;
  for (int t = 0; t < NT; ++t) {
    const unsigned short* At = &sA[buf][0];
    const unsigned short* Bt = &sB[buf][0];
    bf16x8 a[4][2], b[4][2];

    // -- phase 1: read a[m0-3] + all b (24 ds_read); stage (t+1,A1); MFMA Q00
#pragma unroll
    for (int mt = 0; mt < 4; ++mt)
#pragma unroll
      for (int h = 0; h < 2; ++h)
        a[mt][h] = ld_frag(At, wm * 128 + mt * 16 + lrow, h * 4 + quad);
#pragma unroll
    for (int nf = 0; nf < 4; ++nf)
#pragma unroll
      for (int h = 0; h < 2; ++h)
        b[nf][h] = ld_frag(Bt, wn * 64 + nf * 16 + lrow, h * 4 + quad);
    if (t + 1 < NT) stage_half(Ag, &sA[buf ^ 1][0], 1, (t + 1) * BK, K, tid, wave);
    asm volatile("s_waitcnt lgkmcnt(8)" ::: "memory");
    bar();
    asm volatile("s_waitcnt lgkmcnt(0)" ::: "memory");
    __builtin_amdgcn_s_setprio(1);
#pragma unroll
    for (int h = 0; h < 2; ++h)
#pragma unroll
      for (int mt = 0; mt < 4; ++mt)
#pragma unroll
        for (int nf = 0; nf < 2; ++nf)
          acc[mt][nf] = __builtin_amdgcn_mfma_f32_16x16x32_bf16(
              a[mt][h], b[nf][h], acc[mt][nf], 0, 0, 0);
    __builtin_amdgcn_s_setprio(0);
    bar();

    // -- phase 2: stage (t+2,B0) [B-half0 last read in phase 1]; MFMA Q01
    if (t + 2 < NT) stage_half(Bg, &sB[buf][0], 0, (t + 2) * BK, K, tid, wave);
    bar();
    __builtin_amdgcn_s_setprio(1);
#pragma unroll
    for (int h = 0; h < 2; ++h)
#pragma unroll
      for (int mt = 0; mt < 4; ++mt)
#pragma unroll
        for (int nf = 0; nf < 2; ++nf)
          acc[mt][2 + nf] = __builtin_amdgcn_mfma_f32_16x16x32_bf16(
              a[mt][h], b[2 + nf][h], acc[mt][2 + nf], 0, 0, 0);
    __builtin_amdgcn_s_setprio(0);
    bar();

    // -- phase 3: read a[m4-7] (8 ds_read); stage (t+2,B1); MFMA Q10
#pragma unroll
    for (int mt = 0; mt < 4; ++mt)
#pragma unroll
      for (int h = 0; h < 2; ++h)
        a[mt][h] = ld_frag(At, wm * 128 + 64 + mt * 16 + lrow, h * 4 + quad);
    if (t + 2 < NT) stage_half(Bg, &sB[buf][0], 1, (t + 2) * BK, K, tid, wave);
    bar();
    asm volatile("s_waitcnt lgkmcnt(0)" ::: "memory");
    __builtin_amdgcn_s_setprio(1);
#pragma unroll
    for (int h = 0; h < 2; ++h)
#pragma unroll
      for (int mt = 0; mt < 4; ++mt)
#pragma unroll
        for (int nf = 0; nf < 2; ++nf)
          acc[4 + mt][nf] = __builtin_amdgcn_mfma_f32_16x16x32_bf16(
              a[mt][h], b[nf][h], acc[4 + mt][nf], 0, 0, 0);
    __builtin_amdgcn_s_setprio(0);
    bar();

    // -- phase 4: stage (t+2,A0) [A last read in phase 3]; MFMA Q11;
    //    K-tile boundary: counted vmcnt completes exactly tile t+1.
    if (t + 2 < NT) stage_half(Ag, &sA[buf][0], 0, (t + 2) * BK, K, tid, wave);
    bar();
    __builtin_amdgcn_s_setprio(1);
#pragma unroll
    for (int h = 0; h < 2; ++h)
#pragma unroll
      for (int mt = 0; mt < 4; ++mt)
#pragma unroll
        for (int nf = 0; nf < 2; ++nf)
          acc[4 + mt][2 + nf] = __builtin_amdgcn_mfma_f32_16x16x32_bf16(
              a[mt][h], b[2 + nf][h], acc[4 + mt][2 + nf], 0, 0, 0);
    __builtin_amdgcn_s_setprio(0);
    if (t + 2 < NT) asm volatile("s_waitcnt vmcnt(6)" ::: "memory");
    else            asm volatile("s_waitcnt vmcnt(0)" ::: "memory");
    bar();
    buf ^= 1;
  }

  // Epilogue: D[row = quad*4 + r][col = lrow] per 16x16 fragment; add bias.
#pragma unroll
  for (int nf = 0; nf < 4; ++nf) {
    int col = col0 + wn * 64 + nf * 16 + lrow;
    float bv = bias[col];
#pragma unroll
    for (int mf = 0; mf < 8; ++mf) {
      int rowb = row0 + wm * 128 + mf * 16 + quad * 4;
#pragma unroll
      for (int r = 0; r < 4; ++r)
        C[(size_t)(rowb + r) * N + col] = acc[mf][nf][r] + bv;
    }
  }
}

// ---------------- fallback (no workspace): fp32 reg-staged 128^2 ----------------
__global__ void gemm_fallback(const float* __restrict__ Afp,
                              const float* __restrict__ Bfp,
                              const float* __restrict__ bias,
                              float* __restrict__ C, int M, int N, int K) {
  __shared__ unsigned short Als[TILE * BK];
  __shared__ unsigned short Bls[TILE * BK];

  const int tid = threadIdx.x;
  const int wave = tid >> 6;
  const int lane = tid & 63;
  const int lrow = lane & 15;
  const int quad = lane >> 4;
  const int mW = (wave >> 1) * 64;
  const int nW = (wave & 1) * 64;
  const int row0 = blockIdx.y * TILE;
  const int col0 = blockIdx.x * TILE;

  f32x4 acc[4][4];
  const f32x4 zero = {0.f, 0.f, 0.f, 0.f};
#pragma unroll
  for (int i = 0; i < 4; ++i)
#pragma unroll
    for (int j = 0; j < 4; ++j) acc[i][j] = zero;

  for (int k0 = 0; k0 < K; k0 += BK) {
#pragma unroll
    for (int c = 0; c < 4; ++c) {
      int e0 = (c * 256 + tid) * 8;
      int r = e0 >> 6;
      int kc = e0 & 63;
      const float* ga = Afp + (size_t)(row0 + r) * K + k0 + kc;
      const float* gb = Bfp + (size_t)(col0 + r) * K + k0 + kc;
      float4 a0 = ((const float4*)ga)[0];
      float4 a1 = ((const float4*)ga)[1];
      float4 b0 = ((const float4*)gb)[0];
      float4 b1 = ((const float4*)gb)[1];
      union { unsigned short u[8]; uint4 v; } oa, ob;
      oa.u[0] = f2bf(a0.x); oa.u[1] = f2bf(a0.y);
      oa.u[2] = f2bf(a0.z); oa.u[3] = f2bf(a0.w);
      oa.u[4] = f2bf(a1.x); oa.u[5] = f2bf(a1.y);
      oa.u[6] = f2bf(a1.z); oa.u[7] = f2bf(a1.w);
      ob.u[0] = f2bf(b0.x); ob.u[1] = f2bf(b0.y);
      ob.u[2] = f2bf(b0.z); ob.u[3] = f2bf(b0.w);
      ob.u[4] = f2bf(b1.x); ob.u[5] = f2bf(b1.y);
      ob.u[6] = f2bf(b1.z); ob.u[7] = f2bf(b1.w);
      *(uint4*)&Als[e0] = oa.v;
      *(uint4*)&Bls[e0] = ob.v;
    }
    __syncthreads();
#pragma unroll
    for (int h = 0; h < 2; ++h) {
      bf16x8 af[4], bfr[4];
#pragma unroll
      for (int t = 0; t < 4; ++t) {
        af[t]  = *(const bf16x8*)&Als[(mW + t * 16 + lrow) * BK + h * 32 + quad * 8];
        bfr[t] = *(const bf16x8*)&Bls[(nW + t * 16 + lrow) * BK + h * 32 + quad * 8];
      }
#pragma unroll
      for (int mt = 0; mt < 4; ++mt)
#pragma unroll
        for (int nt = 0; nt < 4; ++nt)
          acc[mt][nt] = __builtin_amdgcn_mfma_f32_16x16x32_bf16(
              af[mt], bfr[nt], acc[mt][nt], 0, 0, 0);
    }
    __syncthreads();
  }

#pragma unroll
  for (int nt = 0; nt < 4; ++nt) {
    int col = col0 + nW + nt * 16 + lrow;
    float bv = bias[col];
#pragma unroll
    for (int mt = 0; mt < 4; ++mt) {
      int rowb = row0 + mW + mt * 16 + quad * 4;
#pragma unroll
      for (int r = 0; r < 4; ++r) {
        C[(size_t)(rowb + r) * N + col] = acc[mt][nt][r] + bv;
      }
    }
  }
}

extern "C" void kernel_launch(void* const* d_in, const int* in_sizes, int n_in,
                              void* d_out, int out_size, void* d_ws, size_t ws_size,
                              hipStream_t stream) {
  const int M = 8192, N = 4096, K = 4096;
  const float* x = (const float*)d_in[0];
  const float* wr = (const float*)d_in[1];
  // d_in[2] (weight_imag) is provably unused: mag*cos(phase) == real.
  const float* bias = (const float*)d_in[3];
  float* out = (float*)d_out;

  const size_t nA = (size_t)M * K;
  const size_t nB = (size_t)N * K;

  if (ws_size >= (nA + nB) * sizeof(unsigned short)) {
    unsigned short* xa = (unsigned short*)d_ws;
    unsigned short* wb = xa + nA;
    hipLaunchKernelGGL(cvt_both_f32_to_bf16, dim3(4096), dim3(256), 0, stream,
                       x, wr, xa, wb, (int)(nA / 8), (int)(nB / 8));
    dim3 grid(N / BN, M / BM);  // 16 x 32 = 512 blocks, 1 per CU
    hipLaunchKernelGGL(gemm256_bt_bf16, grid, dim3(512), 0, stream,
                       xa, wb, bias, out, M, N, K);
  } else {
    dim3 grid(N / TILE, M / TILE);
    hipLaunchKernelGGL(gemm_fallback, grid, dim3(256), 0, stream,
                       x, wr, bias, out, M, N, K);
  }
}